// Round 6
// baseline (999.376 us; speedup 1.0000x reference)
//
#include <hip/hip_runtime.h>
#include <float.h>
#include <math.h>
#include <stdint.h>

// Problem constants (match reference)
constexpr int B   = 8;
constexpr int C   = 96;
constexpr int N   = 3136;   // 56*56
constexpr int M   = 784;    // RATIO*N
constexpr int C4  = 384;    // 4*C
constexpr int OUT = 192;
constexpr int KD  = 16;     // K_DPC
constexpr int TK  = 5;      // TOPK
constexpr int NSPLIT = 7;   // k_agg split-N factor (N/7 = 448 = 7*64)

constexpr int NT16 = N / 16;   // 196 column tiles of 16

typedef __attribute__((ext_vector_type(8))) short v8s;   // 8 bf16 (4 VGPR)
typedef __attribute__((ext_vector_type(4))) float v4f;   // 4 fp32 acc

// ---------------------------------------------------------------------------
// fp32 round-to-nearest of a positive double WITH flush-to-zero of subnormal
// results (validated semantics for the reference's exp underflow).
__device__ inline uint32_t f32q_ftz(double t) {
    if (t <= 0.0) return 0u;
    float f = (float)t;              // exact RN cvt (double->float)
    if (f < 0x1p-126f) return 0u;    // subnormal result -> flush to zero
    return __float_as_uint(f);
}

// fp32 -> bf16 round-to-nearest-even
__device__ inline ushort f2bf(float f) {
    uint32_t u = __float_as_uint(f);
    uint32_t r = (u + 0x7fffu + ((u >> 16) & 1u)) >> 16;
    return (ushort)r;
}

// ---------------------------------------------------------------------------
// K0: per-point squared norms of y and x (both laid out (B,C,N))
__global__ __launch_bounds__(256) void k_norms(const float* __restrict__ y,
                                               const float* __restrict__ x,
                                               float* __restrict__ ynorm,
                                               float* __restrict__ xnorm) {
    int id = blockIdx.x * 256 + threadIdx.x;
    if (id >= B * N) return;
    int b = id / N, n = id % N;
    const float* yb = y + (size_t)b * C * N + n;
    const float* xb = x + (size_t)b * C * N + n;
    float sy = 0.f, sx = 0.f;
    #pragma unroll 8
    for (int c = 0; c < C; ++c) {
        float a = yb[(size_t)c * N]; sy += a * a;
        float d = xb[(size_t)c * N]; sx += d * d;
    }
    ynorm[id] = sy;
    xnorm[id] = sx;
}

// ---------------------------------------------------------------------------
// K-TR: tiled transpose of y and x into [b][n][c] layout.
__global__ __launch_bounds__(256) void k_tr(const float* __restrict__ y,
                                            const float* __restrict__ x,
                                            float* __restrict__ yT,
                                            float* __restrict__ xT) {
    __shared__ float ty[32][33];
    __shared__ float tx[32][33];
    const int b  = blockIdx.z;
    const int n0 = blockIdx.x * 32;
    const int c0 = blockIdx.y * 32;
    const int tn = threadIdx.x & 31;
    const int tc = threadIdx.x >> 5;   // 0..7
    #pragma unroll
    for (int k = 0; k < 4; ++k) {
        int c = c0 + tc + 8 * k;
        ty[tc + 8 * k][tn] = y[((size_t)b * C + c) * N + n0 + tn];
        tx[tc + 8 * k][tn] = x[((size_t)b * C + c) * N + n0 + tn];
    }
    __syncthreads();
    #pragma unroll
    for (int k = 0; k < 4; ++k) {
        int n = n0 + tc + 8 * k;
        yT[((size_t)b * N + n) * C + c0 + tn] = ty[tn][tc + 8 * k];
        xT[((size_t)b * N + n) * C + c0 + tn] = tx[tn][tc + 8 * k];
    }
}

// ---------------------------------------------------------------------------
// K-FRAG: pre-pack y into bf16 MFMA B-fragment order.
__global__ __launch_bounds__(192) void k_yfrag(const float* __restrict__ y,
                                               ushort* __restrict__ yfrag) {
    const int tile = blockIdx.x;          // 0..195
    const int b    = blockIdx.y;
    const int kc   = threadIdx.x >> 6;    // 0..2
    const int l    = threadIdx.x & 63;
    const int lg   = l >> 4, lc = l & 15;
    const float* yb = y + (size_t)b * C * N;
    ushort out[8];
    #pragma unroll
    for (int e = 0; e < 8; ++e)
        out[e] = f2bf(yb[(size_t)(kc * 32 + lg * 8 + e) * N + tile * 16 + lc]);
    ushort* dst = yfrag + ((((size_t)b * NT16 + tile) * 3 + kc) * 64 + l) * 8;
    *reinterpret_cast<uint4*>(dst) = *reinterpret_cast<const uint4*>(out);
}

constexpr int DR = 8;       // rows per block (fallback kernel)
constexpr int DCOLS = 1024; // cols per tile (fallback kernel)
constexpr int DCAP = 96;    // candidate capacity per row (MFMA kernel)

// ---------------------------------------------------------------------------
// K1 vMFMA4: round-4 unsplit structure (validated) + register double-buffer
// pipelining: iteration p+1's 3 bfr vectors and 4 rel scalars are issued at
// the TOP of iteration p, before p's vmcnt wait -> one L2/L3 round-trip per
// iteration hides under p's MFMA + epilogue. Numerics bit-identical to v2.
__global__ __launch_bounds__(256) void k_density_mfma(
        const float* __restrict__ yT,
        const ushort* __restrict__ yfrag,
        const float* __restrict__ rel,
        const float* __restrict__ ynorm,
        uint32_t* __restrict__ densbits,
        float* __restrict__ rowmax) {
    const int b  = blockIdx.y;
    const int i0 = blockIdx.x * 16;
    const int t  = threadIdx.x;
    const int w  = t >> 6;       // wave 0..3
    const int l  = t & 63;       // lane
    const int lg = l >> 4;       // lane group 0..3
    const int lc = l & 15;       // col-in-tile / A-row index

    __shared__ float ynS[N];          // whole ynorm row for batch b (12.5 KB)
    __shared__ float s16[16][17];
    __shared__ float thrS[16];
    __shared__ float candV[16][DCAP + 1];   // +1 pad: conflict-free merge
    __shared__ int   candC[16];
    __shared__ float rmS[4][16];

    for (int e = t; e < N / 4; e += 256)
        *reinterpret_cast<float4*>(&ynS[e * 4]) =
            *reinterpret_cast<const float4*>(ynorm + (size_t)b * N + e * 4);

    if (t < 16) {
        thrS[t] = FLT_MAX;
        candC[t] = 0;
        #pragma unroll
        for (int q = 0; q < 16; ++q) s16[t][q] = FLT_MAX;
    }

    // A fragments: rows i0 + lc; k = kc*32 + lg*8 + e  (once per block)
    v8s afr[3];
    {
        const float* ap = yT + ((size_t)b * N + i0 + lc) * C + lg * 8;
        #pragma unroll
        for (int kc = 0; kc < 3; ++kc) {
            float4 f0 = *reinterpret_cast<const float4*>(ap + kc * 32);
            float4 f1 = *reinterpret_cast<const float4*>(ap + kc * 32 + 4);
            v8s a;
            a[0] = (short)f2bf(f0.x); a[1] = (short)f2bf(f0.y);
            a[2] = (short)f2bf(f0.z); a[3] = (short)f2bf(f0.w);
            a[4] = (short)f2bf(f1.x); a[5] = (short)f2bf(f1.y);
            a[6] = (short)f2bf(f1.z); a[7] = (short)f2bf(f1.w);
            afr[kc] = a;
        }
    }

    __syncthreads();

    float ni[4];
    #pragma unroll
    for (int q = 0; q < 4; ++q)
        ni[q] = ynS[i0 + lg * 4 + q];

    float rm[4], thr[4];
    #pragma unroll
    for (int q = 0; q < 4; ++q) { rm[q] = -FLT_MAX; thr[q] = FLT_MAX; }

    // per-lane rel pointers (col base w*16+lc, advance 64 floats per p)
    const float* rp[4];
    #pragma unroll
    for (int q = 0; q < 4; ++q)
        rp[q] = rel + (size_t)(i0 + lg * 4 + q) * N + w * 16 + lc;

    const ushort* yfb = yfrag + (size_t)b * NT16 * 3 * 64 * 8;

    // ---- prologue: preload p = 0 operands
    v8s bA[3];
    float rlA[4];
    {
        const int tile = w;                  // p = 0
        #pragma unroll
        for (int kc = 0; kc < 3; ++kc)
            bA[kc] = *reinterpret_cast<const v8s*>(
                yfb + (((size_t)tile * 3 + kc) * 64 + l) * 8);
        #pragma unroll
        for (int q = 0; q < 4; ++q) rlA[q] = rp[q][0];
    }

    #pragma unroll 1
    for (int p = 0; p < 49; ++p) {
        const bool more = (p < 48);

        // ---- issue next iteration's loads FIRST (stay in flight over
        //      this iteration's vmcnt wait + compute)
        v8s bB[3];
        float rlB[4];
        if (more) {
            const int tn = (p + 1) * 4 + w;
            #pragma unroll
            for (int kc = 0; kc < 3; ++kc)
                bB[kc] = *reinterpret_cast<const v8s*>(
                    yfb + (((size_t)tn * 3 + kc) * 64 + l) * 8);
            #pragma unroll
            for (int q = 0; q < 4; ++q) rlB[q] = rp[q][64];
        }

        // ---- compute current tile from the A buffers
        const int tile = p * 4 + w;
        const int jt = tile * 16;

        v4f acc;
        acc[0] = 0.f; acc[1] = 0.f; acc[2] = 0.f; acc[3] = 0.f;
        #pragma unroll
        for (int kc = 0; kc < 3; ++kc)
            acc = __builtin_amdgcn_mfma_f32_16x16x32_bf16(afr[kc], bA[kc], acc, 0, 0, 0);

        const float nj = ynS[jt + lc];

        #pragma unroll
        for (int q = 0; q < 4; ++q) {
            const int row = lg * 4 + q;
            const float v = ni[q] + nj - 2.f * acc[q] + rlA[q];
            rm[q] = fmaxf(rm[q], v);
            if (p == 0) {
                candV[row][w * 16 + lc] = v;   // deterministic slots
            } else if (v < thr[q]) {
                int pos = atomicAdd(&candC[row], 1);
                if (pos < DCAP) candV[row][pos] = v;
            }
        }

        const bool domerge = (p <= 3) || (p == 9) || (p == 19) || (p == 33) || (p == 48);
        if (domerge) {
            __syncthreads();
            if (t < 16) {
                int cnt = (p == 0) ? 64 : candC[t];
                if (cnt > DCAP) cnt = DCAP;
                for (int qq = 0; qq < cnt; ++qq) {
                    float v = candV[t][qq];
                    if (v < s16[t][15]) {
                        int pos = 15;
                        while (pos > 0 && s16[t][pos - 1] > v) {
                            s16[t][pos] = s16[t][pos - 1];
                            --pos;
                        }
                        s16[t][pos] = v;
                    }
                }
                candC[t] = 0;
                thrS[t] = s16[t][15];
            }
            __syncthreads();
            #pragma unroll
            for (int q = 0; q < 4; ++q)
                thr[q] = thrS[lg * 4 + q];
        }

        // ---- rotate buffers
        if (more) {
            #pragma unroll
            for (int kc = 0; kc < 3; ++kc) bA[kc] = bB[kc];
            #pragma unroll
            for (int q = 0; q < 4; ++q) { rlA[q] = rlB[q]; rp[q] += 64; }
        }
    }

    // rowmax: reduce over the 16 col-lanes of each group, then across waves
    #pragma unroll
    for (int q = 0; q < 4; ++q) {
        float v = rm[q];
        #pragma unroll
        for (int off = 1; off < 16; off <<= 1)
            v = fmaxf(v, __shfl_xor(v, off, 64));
        rm[q] = v;
    }
    if (lc == 0) {
        #pragma unroll
        for (int q = 0; q < 4; ++q)
            rmS[w][lg * 4 + q] = rm[q];
    }
    __syncthreads();

    if (t < 16) {
        float mx = fmaxf(fmaxf(rmS[0][t], rmS[1][t]), fmaxf(rmS[2][t], rmS[3][t]));
        rowmax[b * N + i0 + t] = mx;
        float r8[8];
        #pragma unroll
        for (int j2 = 0; j2 < 8; ++j2) r8[j2] = s16[t][j2] + s16[t][8 + j2];
        float s = ((r8[0] + r8[1]) + (r8[2] + r8[3]))
                + ((r8[4] + r8[5]) + (r8[6] + r8[7]));
        float mean = s * (1.0f / 16.0f);
        densbits[b * N + i0 + t] = f32q_ftz(exp(-(double)mean));
    }
}

// ---------------------------------------------------------------------------
// K1 v6 (fallback, validated round 10)
__global__ __launch_bounds__(256) void k_density(const float* __restrict__ y,
                                                 const float* __restrict__ rel,
                                                 const float* __restrict__ ynorm,
                                                 uint32_t* __restrict__ densbits,
                                                 float* __restrict__ rowmax) {
    const int b  = blockIdx.y;
    const int i0 = blockIdx.x * DR;
    const int t  = threadIdx.x;

    __shared__ __align__(16) float yiS[DR][100];
    __shared__ float niS[DR];
    __shared__ float s16[DR][17];
    __shared__ float thrS[DR];
    __shared__ float minb[DR][257];
    __shared__ float candV[DR][193];
    __shared__ int   candC[DR];

    const float* yb = y + (size_t)b * C * N;

    for (int e = t; e < C * 2; e += 256) {
        int c = e >> 1, n4 = (e & 1) << 2;
        float4 v = *reinterpret_cast<const float4*>(yb + (size_t)c * N + i0 + n4);
        yiS[n4 + 0][c] = v.x;
        yiS[n4 + 1][c] = v.y;
        yiS[n4 + 2][c] = v.z;
        yiS[n4 + 3][c] = v.w;
    }
    if (t < DR) {
        niS[t] = ynorm[b * N + i0 + t];
        thrS[t] = FLT_MAX;
        candC[t] = 0;
        #pragma unroll
        for (int q = 0; q < 16; ++q) s16[t][q] = FLT_MAX;
    }
    float rm[DR];
    #pragma unroll
    for (int r = 0; r < DR; ++r) rm[r] = -FLT_MAX;
    __syncthreads();

    for (int tile = 0; tile < 4; ++tile) {
        const int jt = tile * DCOLS + 4 * t;
        const bool active = (jt < N);

        float acc[DR][4];
        #pragma unroll
        for (int r = 0; r < DR; ++r)
            #pragma unroll
            for (int q = 0; q < 4; ++q) acc[r][q] = 0.f;

        float dv[DR][4];

        if (active) {
            for (int c0 = 0; c0 < C; c0 += 4) {
                float4 bq0 = *reinterpret_cast<const float4*>(yb + (size_t)(c0 + 0) * N + jt);
                float4 bq1 = *reinterpret_cast<const float4*>(yb + (size_t)(c0 + 1) * N + jt);
                float4 bq2 = *reinterpret_cast<const float4*>(yb + (size_t)(c0 + 2) * N + jt);
                float4 bq3 = *reinterpret_cast<const float4*>(yb + (size_t)(c0 + 3) * N + jt);
                #pragma unroll
                for (int r = 0; r < DR; ++r) {
                    float4 a4 = *reinterpret_cast<const float4*>(&yiS[r][c0]);
                    acc[r][0] += a4.x * bq0.x; acc[r][1] += a4.x * bq0.y;
                    acc[r][2] += a4.x * bq0.z; acc[r][3] += a4.x * bq0.w;
                    acc[r][0] += a4.y * bq1.x; acc[r][1] += a4.y * bq1.y;
                    acc[r][2] += a4.y * bq1.z; acc[r][3] += a4.y * bq1.w;
                    acc[r][0] += a4.z * bq2.x; acc[r][1] += a4.z * bq2.y;
                    acc[r][2] += a4.z * bq2.z; acc[r][3] += a4.z * bq2.w;
                    acc[r][0] += a4.w * bq3.x; acc[r][1] += a4.w * bq3.y;
                    acc[r][2] += a4.w * bq3.z; acc[r][3] += a4.w * bq3.w;
                }
            }

            float4 yn4 = *reinterpret_cast<const float4*>(ynorm + (size_t)b * N + jt);
            float yn[4] = {yn4.x, yn4.y, yn4.z, yn4.w};
            #pragma unroll
            for (int r = 0; r < DR; ++r) {
                float4 rl4 = *reinterpret_cast<const float4*>(rel + (size_t)(i0 + r) * N + jt);
                float rl[4] = {rl4.x, rl4.y, rl4.z, rl4.w};
                float niv = niS[r];
                #pragma unroll
                for (int q = 0; q < 4; ++q)
                    dv[r][q] = niv + yn[q] - 2.f * acc[r][q] + rl[q];
                rm[r] = fmaxf(rm[r],
                        fmaxf(fmaxf(dv[r][0], dv[r][1]), fmaxf(dv[r][2], dv[r][3])));
            }
        }

        if (tile == 0) {
            #pragma unroll
            for (int r = 0; r < DR; ++r) {
                float mn = active
                    ? fminf(fminf(dv[r][0], dv[r][1]), fminf(dv[r][2], dv[r][3]))
                    : FLT_MAX;
                minb[r][t] = mn;
            }
            __syncthreads();
            if (t < DR) {
                #pragma unroll
                for (int q = 0; q < 16; ++q) candV[t][q] = FLT_MAX;
                for (int e = 0; e < 256; ++e) {
                    float v = minb[t][e];
                    if (v < candV[t][15]) {
                        int pos = 15;
                        while (pos > 0 && candV[t][pos - 1] > v) {
                            candV[t][pos] = candV[t][pos - 1];
                            --pos;
                        }
                        candV[t][pos] = v;
                    }
                }
                thrS[t] = candV[t][15];
            }
            __syncthreads();
        }

        if (active) {
            #pragma unroll
            for (int r = 0; r < DR; ++r) {
                float thr = thrS[r];
                #pragma unroll
                for (int q = 0; q < 4; ++q) {
                    float v = dv[r][q];
                    bool take = (tile == 0) ? (v <= thr) : (v < thr);
                    if (take) {
                        int p = atomicAdd(&candC[r], 1);
                        if (p < 192) candV[r][p] = v;
                    }
                }
            }
        }
        __syncthreads();

        if (t < DR) {
            int cnt = candC[t];
            if (cnt > 192) cnt = 192;
            for (int qq = 0; qq < cnt; ++qq) {
                float v = candV[t][qq];
                if (v < s16[t][15]) {
                    int pos = 15;
                    while (pos > 0 && s16[t][pos - 1] > v) {
                        s16[t][pos] = s16[t][pos - 1];
                        --pos;
                    }
                    s16[t][pos] = v;
                }
            }
            candC[t] = 0;
            thrS[t] = s16[t][15];
        }
        __syncthreads();
    }

    #pragma unroll
    for (int r = 0; r < DR; ++r) minb[r][t] = rm[r];
    __syncthreads();
    if (t < DR) {
        float mx = -FLT_MAX;
        for (int e = 0; e < 256; ++e) mx = fmaxf(mx, minb[t][e]);
        rowmax[b * N + i0 + t] = mx;

        float r8[8];
        #pragma unroll
        for (int j2 = 0; j2 < 8; ++j2) r8[j2] = s16[t][j2] + s16[t][8 + j2];
        float s = ((r8[0] + r8[1]) + (r8[2] + r8[3]))
                + ((r8[4] + r8[5]) + (r8[6] + r8[7]));
        float mean = s * (1.0f / 16.0f);
        densbits[b * N + i0 + t] = f32q_ftz(exp(-(double)mean));
    }
}

// ---------------------------------------------------------------------------
// K2: per-batch global max of d (fp32)
__global__ __launch_bounds__(256) void k_dmax(const float* __restrict__ rowmax,
                                              float* __restrict__ dmax) {
    int b = blockIdx.x, t = threadIdx.x;
    __shared__ float rv[256];
    float lm = -FLT_MAX;
    for (int j = t; j < N; j += 256) lm = fmaxf(lm, rowmax[b * N + j]);
    rv[t] = lm;
    __syncthreads();
    for (int s = 128; s > 0; s >>= 1) {
        if (t < s) rv[t] = fmaxf(rv[t], rv[t + s]);
        __syncthreads();
    }
    if (t == 0) dmax[b] = rv[0];
}

// ---------------------------------------------------------------------------
// K3: dist_peak = min over j with dens[j] > dens[i] of d[i,j] (else dmax);
// score = fp32(dist_peak * density) emulated exactly; packed rank key.
__global__ __launch_bounds__(256) void k_score(const float* __restrict__ y,
                                               const float* __restrict__ rel,
                                               const float* __restrict__ ynorm,
                                               const uint32_t* __restrict__ densbits,
                                               const float* __restrict__ dmax,
                                               unsigned long long* __restrict__ keys) {
    const int i = blockIdx.x;
    const int b = blockIdx.y;
    const int t = threadIdx.x;

    const uint32_t bi = densbits[b * N + i];
    if (bi == 0u) {
        if (t == 0) keys[b * N + i] =
            (unsigned long long)(0xFFFFFFFFu - (uint32_t)i);
        return;
    }

    __shared__ float yi[C];
    __shared__ float rv[256];

    const float* yb = y + (size_t)b * C * N;
    if (t < C) yi[t] = yb[(size_t)t * N + i];
    __syncthreads();

    const float ni = ynorm[b * N + i];
    float mn = FLT_MAX;
    for (int j = t; j < N; j += 256) {
        if (densbits[b * N + j] > bi) {
            const float* p = yb + j;
            float dot = 0.f;
            #pragma unroll 8
            for (int c = 0; c < C; ++c) dot += yi[c] * p[(size_t)c * N];
            float d = ni + ynorm[b * N + j] - 2.f * dot + rel[(size_t)i * N + j];
            mn = fminf(mn, d);
        }
    }
    rv[t] = mn;
    __syncthreads();
    for (int s = 128; s > 0; s >>= 1) {
        if (t < s) rv[t] = fminf(rv[t], rv[t + s]);
        __syncthreads();
    }
    if (t == 0) {
        float dp = fminf(rv[0], dmax[b]);
        double p = (double)dp * (double)__uint_as_float(bi);
        float sf = (float)p;
        uint32_t sb = (sf < 0x1p-126f) ? 0u : __float_as_uint(sf);
        keys[b * N + i] = ((unsigned long long)sb << 32)
                        | (unsigned long long)(0xFFFFFFFFu - (uint32_t)i);
    }
}

// ---------------------------------------------------------------------------
// K4: per-batch bitonic sort of packed keys, descending -> top M indices.
__global__ __launch_bounds__(1024) void k_topm(const unsigned long long* __restrict__ keys,
                                               int* __restrict__ sidx) {
    constexpr int SZ = 4096;
    int b = blockIdx.x, t = threadIdx.x;
    __shared__ unsigned long long ks[SZ];
    for (int i = t; i < SZ; i += 1024) ks[i] = (i < N) ? keys[b * N + i] : 0ull;
    __syncthreads();
    for (int k = 2; k <= SZ; k <<= 1) {
        for (int j = k >> 1; j > 0; j >>= 1) {
            for (int i = t; i < SZ; i += 1024) {
                int ixj = i ^ j;
                if (ixj > i) {
                    bool up = ((i & k) == 0);
                    unsigned long long a = ks[i], c2 = ks[ixj];
                    bool doSwap = up ? (a < c2) : (a > c2);  // descending
                    if (doSwap) { ks[i] = c2; ks[ixj] = a; }
                }
            }
            __syncthreads();
        }
    }
    for (int m = t; m < M; m += 1024)
        sidx[b * M + m] = (int)(0xFFFFFFFFu - (uint32_t)(ks[m] & 0xFFFFFFFFull));
}

// ---------------------------------------------------------------------------
// K5 v2: gather centers TRANSPOSED: cenT[b][c][m] = y[b][c][sidx[m]].
__global__ __launch_bounds__(256) void k_cen(const float* __restrict__ y,
                                             const int* __restrict__ sidx,
                                             const float* __restrict__ ynorm,
                                             float* __restrict__ cenT,
                                             float* __restrict__ cnorm) {
    const int b = blockIdx.y;
    const int m = blockIdx.x * 256 + threadIdx.x;
    if (m >= M) return;
    const int j = sidx[b * M + m];
    cnorm[b * M + m] = ynorm[b * N + j];
    const float* yb = y + (size_t)b * C * N;
    float* ct = cenT + (size_t)b * C * M;
    #pragma unroll 8
    for (int c = 0; c < C; ++c)
        ct[(size_t)c * M + m] = yb[(size_t)c * N + j];
}

// ---------------------------------------------------------------------------
// K6 v3 (xT path, validated round 11)
__global__ __launch_bounds__(256) void k_assign_t(const float* __restrict__ xT,
                                                  const float* __restrict__ cenT,
                                                  const float* __restrict__ xnorm,
                                                  const float* __restrict__ cnorm,
                                                  float* __restrict__ assign,
                                                  int* __restrict__ nnidx) {
    const int b  = blockIdx.y;
    const int i0 = blockIdx.x * 8;
    const int t  = threadIdx.x;

    __shared__ __align__(16) float Ss[8][788];
    __shared__ float xnS[8];

    const float* xTb = xT + (size_t)b * N * C;
    const float* ct  = cenT + (size_t)b * C * M;

    if (t < 8) xnS[t] = xnorm[b * N + i0 + t];
    __syncthreads();

    if (t < 196) {
        const int mt = 4 * t;
        float acc[8][4];
        #pragma unroll
        for (int r = 0; r < 8; ++r)
            #pragma unroll
            for (int q = 0; q < 4; ++q) acc[r][q] = 0.f;

        for (int c0 = 0; c0 < C; c0 += 4) {
            float4 bq0 = *reinterpret_cast<const float4*>(ct + (size_t)(c0 + 0) * M + mt);
            float4 bq1 = *reinterpret_cast<const float4*>(ct + (size_t)(c0 + 1) * M + mt);
            float4 bq2 = *reinterpret_cast<const float4*>(ct + (size_t)(c0 + 2) * M + mt);
            float4 bq3 = *reinterpret_cast<const float4*>(ct + (size_t)(c0 + 3) * M + mt);
            #pragma unroll
            for (int r = 0; r < 8; ++r) {
                float4 a4 = *reinterpret_cast<const float4*>(
                    xTb + (size_t)(i0 + r) * C + c0);   // wave-uniform addr
                acc[r][0] += a4.x * bq0.x; acc[r][1] += a4.x * bq0.y;
                acc[r][2] += a4.x * bq0.z; acc[r][3] += a4.x * bq0.w;
                acc[r][0] += a4.y * bq1.x; acc[r][1] += a4.y * bq1.y;
                acc[r][2] += a4.y * bq1.z; acc[r][3] += a4.y * bq1.w;
                acc[r][0] += a4.z * bq2.x; acc[r][1] += a4.z * bq2.y;
                acc[r][2] += a4.z * bq2.z; acc[r][3] += a4.z * bq2.w;
                acc[r][0] += a4.w * bq3.x; acc[r][1] += a4.w * bq3.y;
                acc[r][2] += a4.w * bq3.z; acc[r][3] += a4.w * bq3.w;
            }
        }

        float4 cn4 = *reinterpret_cast<const float4*>(cnorm + (size_t)b * M + mt);
        float cn[4] = {cn4.x, cn4.y, cn4.z, cn4.w};
        #pragma unroll
        for (int r = 0; r < 8; ++r) {
            float xn = xnS[r];
            float sv[4];
            #pragma unroll
            for (int q = 0; q < 4; ++q)
                sv[q] = -(xn + cn[q] - 2.f * acc[r][q]);
            *reinterpret_cast<float4*>(&Ss[r][mt]) =
                make_float4(sv[0], sv[1], sv[2], sv[3]);
        }
    }
    __syncthreads();

    const int r = t >> 5;
    const int l = t & 31;

    float lm = -FLT_MAX;
    for (int m = l; m < M; m += 32) lm = fmaxf(lm, Ss[r][m]);
    #pragma unroll
    for (int off = 16; off > 0; off >>= 1)
        lm = fmaxf(lm, __shfl_xor(lm, off, 32));
    const float smax = lm;

    float ls = 0.f;
    for (int m = l; m < M; m += 32) ls += expf(Ss[r][m] - smax);
    #pragma unroll
    for (int off = 16; off > 0; off >>= 1)
        ls += __shfl_xor(ls, off, 32);
    const float inv = 1.f / ls;

    float* arow = assign + ((size_t)b * N + i0 + r) * M;
    for (int m = l; m < M; m += 32) arow[m] = expf(Ss[r][m] - smax) * inv;

    for (int round = 0; round < TK; ++round) {
        float lv = -FLT_MAX; int li = M;
        for (int m = l; m < M; m += 32) {
            float v = Ss[r][m];
            if (v > lv) { lv = v; li = m; }
        }
        #pragma unroll
        for (int off = 16; off > 0; off >>= 1) {
            float ov = __shfl_xor(lv, off, 32);
            int   oi = __shfl_xor(li, off, 32);
            if (ov > lv || (ov == lv && oi < li)) { lv = ov; li = oi; }
        }
        if (l == 0) {
            nnidx[((size_t)b * N + i0 + r) * TK + round] = li;
            Ss[r][li] = -FLT_MAX;
        }
        __syncthreads();
    }
}

// ---------------------------------------------------------------------------
// K6 v2 (fallback, validated round 8)
__global__ __launch_bounds__(256) void k_assign(const float* __restrict__ x,
                                                const float* __restrict__ cenT,
                                                const float* __restrict__ xnorm,
                                                const float* __restrict__ cnorm,
                                                float* __restrict__ assign,
                                                int* __restrict__ nnidx) {
    const int b  = blockIdx.y;
    const int i0 = blockIdx.x * 8;
    const int t  = threadIdx.x;

    __shared__ __align__(16) float xiS[8][100];
    __shared__ __align__(16) float Ss[8][788];
    __shared__ float xnS[8];

    const float* xb = x + (size_t)b * C * N;
    const float* ct = cenT + (size_t)b * C * M;

    for (int e = t; e < C * 2; e += 256) {
        int c = e >> 1, n4 = (e & 1) << 2;
        float4 v = *reinterpret_cast<const float4*>(xb + (size_t)c * N + i0 + n4);
        xiS[n4 + 0][c] = v.x;
        xiS[n4 + 1][c] = v.y;
        xiS[n4 + 2][c] = v.z;
        xiS[n4 + 3][c] = v.w;
    }
    if (t < 8) xnS[t] = xnorm[b * N + i0 + t];
    __syncthreads();

    if (t < 196) {
        const int mt = 4 * t;
        float acc[8][4];
        #pragma unroll
        for (int r = 0; r < 8; ++r)
            #pragma unroll
            for (int q = 0; q < 4; ++q) acc[r][q] = 0.f;

        for (int c0 = 0; c0 < C; c0 += 4) {
            float4 bq0 = *reinterpret_cast<const float4*>(ct + (size_t)(c0 + 0) * M + mt);
            float4 bq1 = *reinterpret_cast<const float4*>(ct + (size_t)(c0 + 1) * M + mt);
            float4 bq2 = *reinterpret_cast<const float4*>(ct + (size_t)(c0 + 2) * M + mt);
            float4 bq3 = *reinterpret_cast<const float4*>(ct + (size_t)(c0 + 3) * M + mt);
            #pragma unroll
            for (int r = 0; r < 8; ++r) {
                float4 a4 = *reinterpret_cast<const float4*>(&xiS[r][c0]);
                acc[r][0] += a4.x * bq0.x; acc[r][1] += a4.x * bq0.y;
                acc[r][2] += a4.x * bq0.z; acc[r][3] += a4.x * bq0.w;
                acc[r][0] += a4.y * bq1.x; acc[r][1] += a4.y * bq1.y;
                acc[r][2] += a4.y * bq1.z; acc[r][3] += a4.y * bq1.w;
                acc[r][0] += a4.z * bq2.x; acc[r][1] += a4.z * bq2.y;
                acc[r][2] += a4.z * bq2.z; acc[r][3] += a4.z * bq2.w;
                acc[r][0] += a4.w * bq3.x; acc[r][1] += a4.w * bq3.y;
                acc[r][2] += a4.w * bq3.z; acc[r][3] += a4.w * bq3.w;
            }
        }

        float4 cn4 = *reinterpret_cast<const float4*>(cnorm + (size_t)b * M + mt);
        float cn[4] = {cn4.x, cn4.y, cn4.z, cn4.w};
        #pragma unroll
        for (int r = 0; r < 8; ++r) {
            float xn = xnS[r];
            float sv[4];
            #pragma unroll
            for (int q = 0; q < 4; ++q)
                sv[q] = -(xn + cn[q] - 2.f * acc[r][q]);
            *reinterpret_cast<float4*>(&Ss[r][mt]) =
                make_float4(sv[0], sv[1], sv[2], sv[3]);
        }
    }
    __syncthreads();

    const int r = t >> 5;
    const int l = t & 31;

    float lm = -FLT_MAX;
    for (int m = l; m < M; m += 32) lm = fmaxf(lm, Ss[r][m]);
    #pragma unroll
    for (int off = 16; off > 0; off >>= 1)
        lm = fmaxf(lm, __shfl_xor(lm, off, 32));
    const float smax = lm;

    float ls = 0.f;
    for (int m = l; m < M; m += 32) ls += expf(Ss[r][m] - smax);
    #pragma unroll
    for (int off = 16; off > 0; off >>= 1)
        ls += __shfl_xor(ls, off, 32);
    const float inv = 1.f / ls;

    float* arow = assign + ((size_t)b * N + i0 + r) * M;
    for (int m = l; m < M; m += 32) arow[m] = expf(Ss[r][m] - smax) * inv;

    for (int round = 0; round < TK; ++round) {
        float lv = -FLT_MAX; int li = M;
        for (int m = l; m < M; m += 32) {
            float v = Ss[r][m];
            if (v > lv) { lv = v; li = m; }
        }
        #pragma unroll
        for (int off = 16; off > 0; off >>= 1) {
            float ov = __shfl_xor(lv, off, 32);
            int   oi = __shfl_xor(li, off, 32);
            if (ov > lv || (ov == lv && oi < li)) { lv = ov; li = oi; }
        }
        if (l == 0) {
            nnidx[((size_t)b * N + i0 + r) * TK + round] = li;
            Ss[r][li] = -FLT_MAX;
        }
        __syncthreads();
    }
}

// ---------------------------------------------------------------------------
// K7a v2: partial agg over an n-slice with 4m x 3c register tiling.
__global__ __launch_bounds__(128) void k_agg_part(const float* __restrict__ assign,
                                                  const float* __restrict__ x,
                                                  float* __restrict__ aggpart,
                                                  float* __restrict__ masspart) {
    const int b = blockIdx.z;
    const int s = blockIdx.y;
    const int m0 = blockIdx.x * 16;
    const int t = threadIdx.x;
    __shared__ __align__(16) float As[64][16];
    __shared__ __align__(16) float Xs[96][68];   // 68-pad: rows 16B-aligned

    const int mm = 4 * (t & 3);        // 0,4,8,12
    const int cc = 3 * (t >> 2);       // 0..93 step 3

    float acc[4][3];
    #pragma unroll
    for (int i = 0; i < 4; ++i)
        #pragma unroll
        for (int j = 0; j < 3; ++j) acc[i][j] = 0.f;
    float massacc = 0.f;

    const int nbeg = s * (N / NSPLIT);
    const int nend = nbeg + (N / NSPLIT);

    for (int n0 = nbeg; n0 < nend; n0 += 64) {
        #pragma unroll
        for (int k = 0; k < 2; ++k) {
            int idx = t + k * 128;
            int nn = idx >> 2, mq = idx & 3;
            *reinterpret_cast<float4*>(&As[nn][4 * mq]) =
                *reinterpret_cast<const float4*>(
                    assign + ((size_t)b * N + n0 + nn) * M + m0 + 4 * mq);
        }
        #pragma unroll
        for (int k = 0; k < 12; ++k) {
            int idx = t + k * 128;
            int c = idx >> 4, nq = idx & 15;
            *reinterpret_cast<float4*>(&Xs[c][4 * nq]) =
                *reinterpret_cast<const float4*>(
                    x + ((size_t)b * C + c) * N + n0 + 4 * nq);
        }
        __syncthreads();

        if (t < 16) {
            #pragma unroll
            for (int nn = 0; nn < 64; ++nn) massacc += As[nn][t];
        }

        #pragma unroll 4
        for (int nn = 0; nn < 64; ++nn) {
            float4 a4 = *reinterpret_cast<const float4*>(&As[nn][mm]);
            float x0 = Xs[cc + 0][nn];
            float x1 = Xs[cc + 1][nn];
            float x2 = Xs[cc + 2][nn];
            acc[0][0] += a4.x * x0; acc[0][1] += a4.x * x1; acc[0][2] += a4.x * x2;
            acc[1][0] += a4.y * x0; acc[1][1] += a4.y * x1; acc[1][2] += a4.y * x2;
            acc[2][0] += a4.z * x0; acc[2][1] += a4.z * x1; acc[2][2] += a4.z * x2;
            acc[3][0] += a4.w * x0; acc[3][1] += a4.w * x1; acc[3][2] += a4.w * x2;
        }
        __syncthreads();
    }
    if (t < 16) masspart[((size_t)b * NSPLIT + s) * M + m0 + t] = massacc;
    float* ap = aggpart + (((size_t)b * NSPLIT + s) * M) * C;
    #pragma unroll
    for (int i = 0; i < 4; ++i)
        #pragma unroll
        for (int j = 0; j < 3; ++j)
            ap[(size_t)(m0 + mm + i) * C + cc + j] = acc[i][j];
}

// ---------------------------------------------------------------------------
// K7b: reduce the NSPLIT partials (fixed s order), divide by mass+1e-6.
__global__ __launch_bounds__(256) void k_aggred(const float* __restrict__ aggpart,
                                                const float* __restrict__ masspart,
                                                float* __restrict__ aggws) {
    const int b = blockIdx.y;
    const int e = blockIdx.x * 256 + threadIdx.x;   // e = m*C + c
    if (e >= M * C) return;
    const int m = e / C;
    float a = 0.f, ms = 0.f;
    #pragma unroll
    for (int s = 0; s < NSPLIT; ++s) {
        a  += aggpart[(((size_t)b * NSPLIT + s) * M) * C + e];
        ms += masspart[((size_t)b * NSPLIT + s) * M + m];
    }
    aggws[(size_t)b * M * C + e] = a / (ms + 1e-6f);
}

// ---------------------------------------------------------------------------
// K8 v2: batched-GEMM FFN. 8 centers/block, 256 threads, register tiling.
__global__ __launch_bounds__(256) void k_ffn(const float* __restrict__ w1,
                                             const float* __restrict__ b1,
                                             const float* __restrict__ g1,
                                             const float* __restrict__ bt1,
                                             const float* __restrict__ w2,
                                             const float* __restrict__ b2,
                                             const float* __restrict__ g2,
                                             const float* __restrict__ bt2,
                                             float* __restrict__ aggws,
                                             float* __restrict__ refined) {
    const int m0 = blockIdx.x * 8;
    const int b  = blockIdx.y;
    const int t  = threadIdx.x;

    __shared__ __align__(16) float arS[8][100];
    __shared__ __align__(16) float hdS[8][388];

    const float* abase = aggws + ((size_t)b * M + m0) * C;
    if (t < 192) {
        float4 v = *reinterpret_cast<const float4*>(abase + 4 * t);
        int e = 4 * t;
        int m = e / C, c = e % C;
        *reinterpret_cast<float4*>(&arS[m][c]) = v;
    }
    __syncthreads();

    {
        const int og = t >> 1;            // 0..127
        const int mg = (t & 1) * 4;       // 0 or 4
        float acc[3][4];
        #pragma unroll
        for (int j = 0; j < 3; ++j)
            #pragma unroll
            for (int i = 0; i < 4; ++i) acc[j][i] = 0.f;

        for (int c0 = 0; c0 < C; c0 += 4) {
            float4 a0 = *reinterpret_cast<const float4*>(&arS[mg + 0][c0]);
            float4 a1 = *reinterpret_cast<const float4*>(&arS[mg + 1][c0]);
            float4 a2 = *reinterpret_cast<const float4*>(&arS[mg + 2][c0]);
            float4 a3 = *reinterpret_cast<const float4*>(&arS[mg + 3][c0]);
            #pragma unroll
            for (int j = 0; j < 3; ++j) {
                float4 w4 = *reinterpret_cast<const float4*>(
                    w1 + (size_t)(og + 128 * j) * C + c0);
                acc[j][0] += w4.x * a0.x; acc[j][0] += w4.y * a0.y;
                acc[j][0] += w4.z * a0.z; acc[j][0] += w4.w * a0.w;
                acc[j][1] += w4.x * a1.x; acc[j][1] += w4.y * a1.y;
                acc[j][1] += w4.z * a1.z; acc[j][1] += w4.w * a1.w;
                acc[j][2] += w4.x * a2.x; acc[j][2] += w4.y * a2.y;
                acc[j][2] += w4.z * a2.z; acc[j][2] += w4.w * a2.w;
                acc[j][3] += w4.x * a3.x; acc[j][3] += w4.y * a3.y;
                acc[j][3] += w4.z * a3.z; acc[j][3] += w4.w * a3.w;
            }
        }
        #pragma unroll
        for (int j = 0; j < 3; ++j) {
            const int o = og + 128 * j;
            const float bb = b1[o], gg = g1[o], bt = bt1[o];
            #pragma unroll
            for (int i = 0; i < 4; ++i) {
                float h = (acc[j][i] + bb) * gg + bt;
                hdS[mg + i][o] = fmaxf(h, 0.f);
            }
        }
    }
    __syncthreads();

    {
        const int m = t >> 5;             // 0..7
        const int l = t & 31;             // c base
        float acc2[3] = {0.f, 0.f, 0.f};

        for (int o0 = 0; o0 < C4; o0 += 4) {
            float4 h4 = *reinterpret_cast<const float4*>(&hdS[m][o0]);
            #pragma unroll
            for (int j = 0; j < 3; ++j) {
                float4 w4 = *reinterpret_cast<const float4*>(
                    w2 + (size_t)(l + 32 * j) * C4 + o0);
                acc2[j] += w4.x * h4.x; acc2[j] += w4.y * h4.y;
                acc2[j] += w4.z * h4.z; acc2[j] += w4.w * h4.w;
            }
        }
        #pragma unroll
        for (int j = 0; j < 3; ++j) {
            const int c = l + 32 * j;
            float f = acc2[j] + b2[c];
            float v = arS[m][c] + (f * g2[c] + bt2[c]);
            aggws[((size_t)b * M + m0 + m) * C + c] = v;
            refined[((size_t)b * C + c) * M + m0 + m] = v;
        }
    }
}

// ---------------------------------------------------------------------------
// K9: rel = max over top-5 agg rows - xf; interleaved xcat;
// out = relu((nn_w @ xcat + nn_b) * g + bt), stored (B, OUT, N)
__global__ __launch_bounds__(256) void k_final(const float* __restrict__ x,
                                               const float* __restrict__ aggws,
                                               const int* __restrict__ nnidx,
                                               const float* __restrict__ nnw,
                                               const float* __restrict__ nnb,
                                               const float* __restrict__ nng,
                                               const float* __restrict__ nnbt,
                                               float* __restrict__ out) {
    const int b = blockIdx.y;
    const int n0 = blockIdx.x * 16;
    const int t = threadIdx.x;
    __shared__ float xc[16][193];
    __shared__ int nid[16 * TK];

    if (t < 16 * TK) nid[t] = nnidx[((size_t)b * N + n0) * TK + t];
    __syncthreads();

    for (int e = t; e < C * 16; e += 256) {
        int c = e >> 4, r = e & 15;
        float xv = x[((size_t)b * C + c) * N + n0 + r];
        float mx = -FLT_MAX;
        #pragma unroll
        for (int k = 0; k < TK; ++k) {
            int j = nid[r * TK + k];
            mx = fmaxf(mx, aggws[((size_t)b * M + j) * C + c]);
        }
        xc[r][2 * c]     = xv;
        xc[r][2 * c + 1] = mx - xv;
    }
    __syncthreads();

    const int r = t & 15;
    const int og = t >> 4;
    #pragma unroll
    for (int oo = 0; oo < 12; ++oo) {
        int o = og + (oo << 4);
        const float* w = nnw + (size_t)o * (2 * C);
        float a = nnb[o];
        #pragma unroll 8
        for (int cc = 0; cc < 2 * C; ++cc) a += w[cc] * xc[r][cc];
        a = a * nng[o] + nnbt[o];
        out[((size_t)b * OUT + o) * N + n0 + r] = fmaxf(a, 0.f);
    }
}

// ---------------------------------------------------------------------------
extern "C" void kernel_launch(void* const* d_in, const int* in_sizes, int n_in,
                              void* d_out, int out_size, void* d_ws, size_t ws_size,
                              hipStream_t stream) {
    const float* x    = (const float*)d_in[0];
    const float* rel  = (const float*)d_in[1];
    const float* y    = (const float*)d_in[2];
    const float* w1   = (const float*)d_in[3];
    const float* b1   = (const float*)d_in[4];
    const float* g1   = (const float*)d_in[5];
    const float* bt1  = (const float*)d_in[6];
    const float* w2   = (const float*)d_in[7];
    const float* b2   = (const float*)d_in[8];
    const float* g2   = (const float*)d_in[9];
    const float* bt2  = (const float*)d_in[10];
    const float* nnw  = (const float*)d_in[11];
    const float* nnb  = (const float*)d_in[12];
    const float* nng  = (const float*)d_in[13];
    const float* nnbt = (const float*)d_in[14];

    float* out     = (float*)d_out;
    float* refined = out + (size_t)B * OUT * N;

    char* w = (char*)d_ws;
    auto alloc = [&](size_t nbytes) -> void* {
        void* p = (void*)w;
        w += (nbytes + 255) & ~(size_t)255;
        return p;
    };
    float*    ynorm    = (float*)   alloc((size_t)B * N * 4);
    float*    xnorm    = (float*)   alloc((size_t)B * N * 4);
    uint32_t* densbits = (uint32_t*)alloc((size_t)B * N * 4);
    float*    rowmax   = (float*)   alloc((size_t)B * N * 4);
    float*    dmaxv    = (float*)   alloc((size_t)B * 4);
    unsigned long long* keys = (unsigned long long*)alloc((size_t)B * N * 8);
    int*      sidx     = (int*)     alloc((size_t)B * M * 4);
    float*    cnorm    = (float*)   alloc((size_t)B * M * 4);
    float*    cenT     = (float*)   alloc((size_t)B * C * M * 4);
    float*    aggws    = (float*)   alloc((size_t)B * M * C * 4);
    int*      nnidx    = (int*)     alloc((size_t)B * N * TK * 4);
    float*    assign   = (float*)   alloc((size_t)B * N * M * 4);
    float*    aggpart  = (float*)   alloc((size_t)B * NSPLIT * M * C * 4);
    float*    masspart = (float*)   alloc((size_t)B * NSPLIT * M * 4);

    // optional transposed + bf16-fragment copies (gated on workspace size)
    size_t used = (size_t)(w - (char*)d_ws);
    size_t tbytes = (size_t)B * N * C * 4;
    size_t fragbytes = (size_t)B * NT16 * 3 * 64 * 8 * sizeof(ushort);
    float* yT = nullptr;
    float* xT = nullptr;
    ushort* yfrag = nullptr;
    if (ws_size >= used + 2 * (tbytes + 256) + (fragbytes + 256)) {
        yT = (float*)alloc(tbytes);
        xT = (float*)alloc(tbytes);
        yfrag = (ushort*)alloc(fragbytes);
    } else if (ws_size >= used + 2 * (tbytes + 256)) {
        yT = (float*)alloc(tbytes);
        xT = (float*)alloc(tbytes);
    }

    if (yT) k_tr<<<dim3(N / 32, C / 32, B), dim3(256), 0, stream>>>(y, x, yT, xT);
    if (yfrag) k_yfrag<<<dim3(NT16, B), dim3(192), 0, stream>>>(y, yfrag);

    k_norms<<<dim3((B * N + 255) / 256), dim3(256), 0, stream>>>(y, x, ynorm, xnorm);

    if (yT && yfrag)
        k_density_mfma<<<dim3(N / 16, B), dim3(256), 0, stream>>>(yT, yfrag, rel, ynorm, densbits, rowmax);
    else
        k_density<<<dim3(N / DR, B), dim3(256), 0, stream>>>(y, rel, ynorm, densbits, rowmax);

    k_dmax<<<dim3(B), dim3(256), 0, stream>>>(rowmax, dmaxv);
    k_score<<<dim3(N, B), dim3(256), 0, stream>>>(y, rel, ynorm, densbits, dmaxv, keys);
    k_topm<<<dim3(B), dim3(1024), 0, stream>>>(keys, sidx);
    k_cen<<<dim3((M + 255) / 256, B), dim3(256), 0, stream>>>(y, sidx, ynorm, cenT, cnorm);

    if (xT)
        k_assign_t<<<dim3(N / 8, B), dim3(256), 0, stream>>>(xT, cenT, xnorm, cnorm, assign, nnidx);
    else
        k_assign<<<dim3(N / 8, B), dim3(256), 0, stream>>>(x, cenT, xnorm, cnorm, assign, nnidx);

    k_agg_part<<<dim3(M / 16, NSPLIT, B), dim3(128), 0, stream>>>(assign, x, aggpart, masspart);
    k_aggred<<<dim3((M * C + 255) / 256, B), dim3(256), 0, stream>>>(aggpart, masspart, aggws);
    k_ffn<<<dim3(M / 8, B), dim3(256), 0, stream>>>(w1, b1, g1, bt1, w2, b2, g2, bt2, aggws, refined);
    k_final<<<dim3(N / 16, B), dim3(256), 0, stream>>>(x, aggws, nnidx, nnw, nnb, nng, nnbt, out);
}

// Round 7
// 862.520 us; speedup vs baseline: 1.1587x; 1.1587x over previous
//
#include <hip/hip_runtime.h>
#include <float.h>
#include <math.h>
#include <stdint.h>

// Problem constants (match reference)
constexpr int B   = 8;
constexpr int C   = 96;
constexpr int N   = 3136;   // 56*56
constexpr int M   = 784;    // RATIO*N
constexpr int C4  = 384;    // 4*C
constexpr int OUT = 192;
constexpr int KD  = 16;     // K_DPC
constexpr int TK  = 5;      // TOPK
constexpr int NSPLIT = 7;   // k_agg split-N factor (N/7 = 448 = 7*64)

constexpr int NT16 = N / 16;   // 196 column tiles of 16

typedef __attribute__((ext_vector_type(8))) short v8s;   // 8 bf16 (4 VGPR)
typedef __attribute__((ext_vector_type(4))) float v4f;   // 4 fp32 acc

// ---------------------------------------------------------------------------
// fp32 round-to-nearest of a positive double WITH flush-to-zero of subnormal
// results (validated semantics for the reference's exp underflow).
__device__ inline uint32_t f32q_ftz(double t) {
    if (t <= 0.0) return 0u;
    float f = (float)t;              // exact RN cvt (double->float)
    if (f < 0x1p-126f) return 0u;    // subnormal result -> flush to zero
    return __float_as_uint(f);
}

// fp32 -> bf16 round-to-nearest-even
__device__ inline ushort f2bf(float f) {
    uint32_t u = __float_as_uint(f);
    uint32_t r = (u + 0x7fffu + ((u >> 16) & 1u)) >> 16;
    return (ushort)r;
}

// ---------------------------------------------------------------------------
// K0: per-point squared norms of y and x (both laid out (B,C,N))
__global__ __launch_bounds__(256) void k_norms(const float* __restrict__ y,
                                               const float* __restrict__ x,
                                               float* __restrict__ ynorm,
                                               float* __restrict__ xnorm) {
    int id = blockIdx.x * 256 + threadIdx.x;
    if (id >= B * N) return;
    int b = id / N, n = id % N;
    const float* yb = y + (size_t)b * C * N + n;
    const float* xb = x + (size_t)b * C * N + n;
    float sy = 0.f, sx = 0.f;
    #pragma unroll 8
    for (int c = 0; c < C; ++c) {
        float a = yb[(size_t)c * N]; sy += a * a;
        float d = xb[(size_t)c * N]; sx += d * d;
    }
    ynorm[id] = sy;
    xnorm[id] = sx;
}

// ---------------------------------------------------------------------------
// K-TR: tiled transpose of y and x into [b][n][c] layout.
__global__ __launch_bounds__(256) void k_tr(const float* __restrict__ y,
                                            const float* __restrict__ x,
                                            float* __restrict__ yT,
                                            float* __restrict__ xT) {
    __shared__ float ty[32][33];
    __shared__ float tx[32][33];
    const int b  = blockIdx.z;
    const int n0 = blockIdx.x * 32;
    const int c0 = blockIdx.y * 32;
    const int tn = threadIdx.x & 31;
    const int tc = threadIdx.x >> 5;   // 0..7
    #pragma unroll
    for (int k = 0; k < 4; ++k) {
        int c = c0 + tc + 8 * k;
        ty[tc + 8 * k][tn] = y[((size_t)b * C + c) * N + n0 + tn];
        tx[tc + 8 * k][tn] = x[((size_t)b * C + c) * N + n0 + tn];
    }
    __syncthreads();
    #pragma unroll
    for (int k = 0; k < 4; ++k) {
        int n = n0 + tc + 8 * k;
        yT[((size_t)b * N + n) * C + c0 + tn] = ty[tn][tc + 8 * k];
        xT[((size_t)b * N + n) * C + c0 + tn] = tx[tn][tc + 8 * k];
    }
}

// ---------------------------------------------------------------------------
// K-FRAG: pre-pack y into bf16 MFMA B-fragment order.
__global__ __launch_bounds__(192) void k_yfrag(const float* __restrict__ y,
                                               ushort* __restrict__ yfrag) {
    const int tile = blockIdx.x;          // 0..195
    const int b    = blockIdx.y;
    const int kc   = threadIdx.x >> 6;    // 0..2
    const int l    = threadIdx.x & 63;
    const int lg   = l >> 4, lc = l & 15;
    const float* yb = y + (size_t)b * C * N;
    ushort out[8];
    #pragma unroll
    for (int e = 0; e < 8; ++e)
        out[e] = f2bf(yb[(size_t)(kc * 32 + lg * 8 + e) * N + tile * 16 + lc]);
    ushort* dst = yfrag + ((((size_t)b * NT16 + tile) * 3 + kc) * 64 + l) * 8;
    *reinterpret_cast<uint4*>(dst) = *reinterpret_cast<const uint4*>(out);
}

constexpr int DR = 8;       // rows per block (fallback kernel)
constexpr int DCOLS = 1024; // cols per tile (fallback kernel)
constexpr int DCAP = 96;    // candidate capacity per row (MFMA kernel)

// ---------------------------------------------------------------------------
// K1 vMFMA5: round-4 validated structure (16 rows/block, grid 196x8) with
// rel-only prefetch (+4 VGPR) and __launch_bounds__(256,8) occupancy pin
// (round-6 lesson: this kernel's perf is monotone in resident waves; any
// register growth past the residency boundary loses more than ILP gains).
// Numerics bit-identical to round-4.
__global__ __launch_bounds__(256, 8) void k_density_mfma(
        const float* __restrict__ yT,
        const ushort* __restrict__ yfrag,
        const float* __restrict__ rel,
        const float* __restrict__ ynorm,
        uint32_t* __restrict__ densbits,
        float* __restrict__ rowmax) {
    const int b  = blockIdx.y;
    const int i0 = blockIdx.x * 16;
    const int t  = threadIdx.x;
    const int w  = t >> 6;       // wave 0..3
    const int l  = t & 63;       // lane
    const int lg = l >> 4;       // lane group 0..3
    const int lc = l & 15;       // col-in-tile / A-row index

    __shared__ float ynS[N];          // whole ynorm row for batch b (12.5 KB)
    __shared__ float s16[16][17];
    __shared__ float thrS[16];
    __shared__ float candV[16][DCAP + 1];   // +1 pad: conflict-free merge
    __shared__ int   candC[16];
    __shared__ float rmS[4][16];

    for (int e = t; e < N / 4; e += 256)
        *reinterpret_cast<float4*>(&ynS[e * 4]) =
            *reinterpret_cast<const float4*>(ynorm + (size_t)b * N + e * 4);

    if (t < 16) {
        thrS[t] = FLT_MAX;
        candC[t] = 0;
        #pragma unroll
        for (int q = 0; q < 16; ++q) s16[t][q] = FLT_MAX;
    }

    // A fragments: rows i0 + lc; k = kc*32 + lg*8 + e  (once per block)
    v8s afr[3];
    {
        const float* ap = yT + ((size_t)b * N + i0 + lc) * C + lg * 8;
        #pragma unroll
        for (int kc = 0; kc < 3; ++kc) {
            float4 f0 = *reinterpret_cast<const float4*>(ap + kc * 32);
            float4 f1 = *reinterpret_cast<const float4*>(ap + kc * 32 + 4);
            v8s a;
            a[0] = (short)f2bf(f0.x); a[1] = (short)f2bf(f0.y);
            a[2] = (short)f2bf(f0.z); a[3] = (short)f2bf(f0.w);
            a[4] = (short)f2bf(f1.x); a[5] = (short)f2bf(f1.y);
            a[6] = (short)f2bf(f1.z); a[7] = (short)f2bf(f1.w);
            afr[kc] = a;
        }
    }

    __syncthreads();

    float ni[4];
    #pragma unroll
    for (int q = 0; q < 4; ++q)
        ni[q] = ynS[i0 + lg * 4 + q];

    float rm[4], thr[4];
    #pragma unroll
    for (int q = 0; q < 4; ++q) { rm[q] = -FLT_MAX; thr[q] = FLT_MAX; }

    // per-lane rel pointers (col base w*16+lc, advance 64 floats per p)
    const float* rp[4];
    #pragma unroll
    for (int q = 0; q < 4; ++q)
        rp[q] = rel + (size_t)(i0 + lg * 4 + q) * N + w * 16 + lc;

    const ushort* yfb = yfrag + (size_t)b * NT16 * 3 * 64 * 8;

    // prologue: preload p=0 rel values (longest-latency operand)
    float rlA[4];
    #pragma unroll
    for (int q = 0; q < 4; ++q) rlA[q] = rp[q][0];

    #pragma unroll 1
    for (int p = 0; p < 49; ++p) {
        const bool more = (p < 48);

        // issue next iteration's rel loads FIRST (one iteration of slack)
        float rlB[4];
        if (more) {
            #pragma unroll
            for (int q = 0; q < 4; ++q) rlB[q] = rp[q][64];
        }

        const int tile = p * 4 + w;        // 196 tiles, balanced across waves
        const int jt = tile * 16;

        v8s bfr[3];
        #pragma unroll
        for (int kc = 0; kc < 3; ++kc)
            bfr[kc] = *reinterpret_cast<const v8s*>(
                yfb + (((size_t)tile * 3 + kc) * 64 + l) * 8);

        v4f acc;
        acc[0] = 0.f; acc[1] = 0.f; acc[2] = 0.f; acc[3] = 0.f;
        #pragma unroll
        for (int kc = 0; kc < 3; ++kc)
            acc = __builtin_amdgcn_mfma_f32_16x16x32_bf16(afr[kc], bfr[kc], acc, 0, 0, 0);

        const float nj = ynS[jt + lc];

        #pragma unroll
        for (int q = 0; q < 4; ++q) {
            const int row = lg * 4 + q;
            const float v = ni[q] + nj - 2.f * acc[q] + rlA[q];
            rm[q] = fmaxf(rm[q], v);
            if (p == 0) {
                candV[row][w * 16 + lc] = v;   // deterministic slots
            } else if (v < thr[q]) {
                int pos = atomicAdd(&candC[row], 1);
                if (pos < DCAP) candV[row][pos] = v;
            }
        }

        const bool domerge = (p <= 3) || (p == 9) || (p == 19) || (p == 33) || (p == 48);
        if (domerge) {
            __syncthreads();
            if (t < 16) {
                int cnt = (p == 0) ? 64 : candC[t];
                if (cnt > DCAP) cnt = DCAP;
                for (int qq = 0; qq < cnt; ++qq) {
                    float v = candV[t][qq];
                    if (v < s16[t][15]) {
                        int pos = 15;
                        while (pos > 0 && s16[t][pos - 1] > v) {
                            s16[t][pos] = s16[t][pos - 1];
                            --pos;
                        }
                        s16[t][pos] = v;
                    }
                }
                candC[t] = 0;
                thrS[t] = s16[t][15];
            }
            __syncthreads();
            #pragma unroll
            for (int q = 0; q < 4; ++q)
                thr[q] = thrS[lg * 4 + q];
        }

        if (more) {
            #pragma unroll
            for (int q = 0; q < 4; ++q) { rlA[q] = rlB[q]; rp[q] += 64; }
        }
    }

    // rowmax: reduce over the 16 col-lanes of each group, then across waves
    #pragma unroll
    for (int q = 0; q < 4; ++q) {
        float v = rm[q];
        #pragma unroll
        for (int off = 1; off < 16; off <<= 1)
            v = fmaxf(v, __shfl_xor(v, off, 64));
        rm[q] = v;
    }
    if (lc == 0) {
        #pragma unroll
        for (int q = 0; q < 4; ++q)
            rmS[w][lg * 4 + q] = rm[q];
    }
    __syncthreads();

    if (t < 16) {
        float mx = fmaxf(fmaxf(rmS[0][t], rmS[1][t]), fmaxf(rmS[2][t], rmS[3][t]));
        rowmax[b * N + i0 + t] = mx;
        float r8[8];
        #pragma unroll
        for (int j2 = 0; j2 < 8; ++j2) r8[j2] = s16[t][j2] + s16[t][8 + j2];
        float s = ((r8[0] + r8[1]) + (r8[2] + r8[3]))
                + ((r8[4] + r8[5]) + (r8[6] + r8[7]));
        float mean = s * (1.0f / 16.0f);
        densbits[b * N + i0 + t] = f32q_ftz(exp(-(double)mean));
    }
}

// ---------------------------------------------------------------------------
// K1 v6 (fallback, validated round 10)
__global__ __launch_bounds__(256) void k_density(const float* __restrict__ y,
                                                 const float* __restrict__ rel,
                                                 const float* __restrict__ ynorm,
                                                 uint32_t* __restrict__ densbits,
                                                 float* __restrict__ rowmax) {
    const int b  = blockIdx.y;
    const int i0 = blockIdx.x * DR;
    const int t  = threadIdx.x;

    __shared__ __align__(16) float yiS[DR][100];
    __shared__ float niS[DR];
    __shared__ float s16[DR][17];
    __shared__ float thrS[DR];
    __shared__ float minb[DR][257];
    __shared__ float candV[DR][193];
    __shared__ int   candC[DR];

    const float* yb = y + (size_t)b * C * N;

    for (int e = t; e < C * 2; e += 256) {
        int c = e >> 1, n4 = (e & 1) << 2;
        float4 v = *reinterpret_cast<const float4*>(yb + (size_t)c * N + i0 + n4);
        yiS[n4 + 0][c] = v.x;
        yiS[n4 + 1][c] = v.y;
        yiS[n4 + 2][c] = v.z;
        yiS[n4 + 3][c] = v.w;
    }
    if (t < DR) {
        niS[t] = ynorm[b * N + i0 + t];
        thrS[t] = FLT_MAX;
        candC[t] = 0;
        #pragma unroll
        for (int q = 0; q < 16; ++q) s16[t][q] = FLT_MAX;
    }
    float rm[DR];
    #pragma unroll
    for (int r = 0; r < DR; ++r) rm[r] = -FLT_MAX;
    __syncthreads();

    for (int tile = 0; tile < 4; ++tile) {
        const int jt = tile * DCOLS + 4 * t;
        const bool active = (jt < N);

        float acc[DR][4];
        #pragma unroll
        for (int r = 0; r < DR; ++r)
            #pragma unroll
            for (int q = 0; q < 4; ++q) acc[r][q] = 0.f;

        float dv[DR][4];

        if (active) {
            for (int c0 = 0; c0 < C; c0 += 4) {
                float4 bq0 = *reinterpret_cast<const float4*>(yb + (size_t)(c0 + 0) * N + jt);
                float4 bq1 = *reinterpret_cast<const float4*>(yb + (size_t)(c0 + 1) * N + jt);
                float4 bq2 = *reinterpret_cast<const float4*>(yb + (size_t)(c0 + 2) * N + jt);
                float4 bq3 = *reinterpret_cast<const float4*>(yb + (size_t)(c0 + 3) * N + jt);
                #pragma unroll
                for (int r = 0; r < DR; ++r) {
                    float4 a4 = *reinterpret_cast<const float4*>(&yiS[r][c0]);
                    acc[r][0] += a4.x * bq0.x; acc[r][1] += a4.x * bq0.y;
                    acc[r][2] += a4.x * bq0.z; acc[r][3] += a4.x * bq0.w;
                    acc[r][0] += a4.y * bq1.x; acc[r][1] += a4.y * bq1.y;
                    acc[r][2] += a4.y * bq1.z; acc[r][3] += a4.y * bq1.w;
                    acc[r][0] += a4.z * bq2.x; acc[r][1] += a4.z * bq2.y;
                    acc[r][2] += a4.z * bq2.z; acc[r][3] += a4.z * bq2.w;
                    acc[r][0] += a4.w * bq3.x; acc[r][1] += a4.w * bq3.y;
                    acc[r][2] += a4.w * bq3.z; acc[r][3] += a4.w * bq3.w;
                }
            }

            float4 yn4 = *reinterpret_cast<const float4*>(ynorm + (size_t)b * N + jt);
            float yn[4] = {yn4.x, yn4.y, yn4.z, yn4.w};
            #pragma unroll
            for (int r = 0; r < DR; ++r) {
                float4 rl4 = *reinterpret_cast<const float4*>(rel + (size_t)(i0 + r) * N + jt);
                float rl[4] = {rl4.x, rl4.y, rl4.z, rl4.w};
                float niv = niS[r];
                #pragma unroll
                for (int q = 0; q < 4; ++q)
                    dv[r][q] = niv + yn[q] - 2.f * acc[r][q] + rl[q];
                rm[r] = fmaxf(rm[r],
                        fmaxf(fmaxf(dv[r][0], dv[r][1]), fmaxf(dv[r][2], dv[r][3])));
            }
        }

        if (tile == 0) {
            #pragma unroll
            for (int r = 0; r < DR; ++r) {
                float mn = active
                    ? fminf(fminf(dv[r][0], dv[r][1]), fminf(dv[r][2], dv[r][3]))
                    : FLT_MAX;
                minb[r][t] = mn;
            }
            __syncthreads();
            if (t < DR) {
                #pragma unroll
                for (int q = 0; q < 16; ++q) candV[t][q] = FLT_MAX;
                for (int e = 0; e < 256; ++e) {
                    float v = minb[t][e];
                    if (v < candV[t][15]) {
                        int pos = 15;
                        while (pos > 0 && candV[t][pos - 1] > v) {
                            candV[t][pos] = candV[t][pos - 1];
                            --pos;
                        }
                        candV[t][pos] = v;
                    }
                }
                thrS[t] = candV[t][15];
            }
            __syncthreads();
        }

        if (active) {
            #pragma unroll
            for (int r = 0; r < DR; ++r) {
                float thr = thrS[r];
                #pragma unroll
                for (int q = 0; q < 4; ++q) {
                    float v = dv[r][q];
                    bool take = (tile == 0) ? (v <= thr) : (v < thr);
                    if (take) {
                        int p = atomicAdd(&candC[r], 1);
                        if (p < 192) candV[r][p] = v;
                    }
                }
            }
        }
        __syncthreads();

        if (t < DR) {
            int cnt = candC[t];
            if (cnt > 192) cnt = 192;
            for (int qq = 0; qq < cnt; ++qq) {
                float v = candV[t][qq];
                if (v < s16[t][15]) {
                    int pos = 15;
                    while (pos > 0 && s16[t][pos - 1] > v) {
                        s16[t][pos] = s16[t][pos - 1];
                        --pos;
                    }
                    s16[t][pos] = v;
                }
            }
            candC[t] = 0;
            thrS[t] = s16[t][15];
        }
        __syncthreads();
    }

    #pragma unroll
    for (int r = 0; r < DR; ++r) minb[r][t] = rm[r];
    __syncthreads();
    if (t < DR) {
        float mx = -FLT_MAX;
        for (int e = 0; e < 256; ++e) mx = fmaxf(mx, minb[t][e]);
        rowmax[b * N + i0 + t] = mx;

        float r8[8];
        #pragma unroll
        for (int j2 = 0; j2 < 8; ++j2) r8[j2] = s16[t][j2] + s16[t][8 + j2];
        float s = ((r8[0] + r8[1]) + (r8[2] + r8[3]))
                + ((r8[4] + r8[5]) + (r8[6] + r8[7]));
        float mean = s * (1.0f / 16.0f);
        densbits[b * N + i0 + t] = f32q_ftz(exp(-(double)mean));
    }
}

// ---------------------------------------------------------------------------
// K2: per-batch global max of d (fp32)
__global__ __launch_bounds__(256) void k_dmax(const float* __restrict__ rowmax,
                                              float* __restrict__ dmax) {
    int b = blockIdx.x, t = threadIdx.x;
    __shared__ float rv[256];
    float lm = -FLT_MAX;
    for (int j = t; j < N; j += 256) lm = fmaxf(lm, rowmax[b * N + j]);
    rv[t] = lm;
    __syncthreads();
    for (int s = 128; s > 0; s >>= 1) {
        if (t < s) rv[t] = fmaxf(rv[t], rv[t + s]);
        __syncthreads();
    }
    if (t == 0) dmax[b] = rv[0];
}

// ---------------------------------------------------------------------------
// K3: dist_peak = min over j with dens[j] > dens[i] of d[i,j] (else dmax);
// score = fp32(dist_peak * density) emulated exactly; packed rank key.
__global__ __launch_bounds__(256) void k_score(const float* __restrict__ y,
                                               const float* __restrict__ rel,
                                               const float* __restrict__ ynorm,
                                               const uint32_t* __restrict__ densbits,
                                               const float* __restrict__ dmax,
                                               unsigned long long* __restrict__ keys) {
    const int i = blockIdx.x;
    const int b = blockIdx.y;
    const int t = threadIdx.x;

    const uint32_t bi = densbits[b * N + i];
    if (bi == 0u) {
        if (t == 0) keys[b * N + i] =
            (unsigned long long)(0xFFFFFFFFu - (uint32_t)i);
        return;
    }

    __shared__ float yi[C];
    __shared__ float rv[256];

    const float* yb = y + (size_t)b * C * N;
    if (t < C) yi[t] = yb[(size_t)t * N + i];
    __syncthreads();

    const float ni = ynorm[b * N + i];
    float mn = FLT_MAX;
    for (int j = t; j < N; j += 256) {
        if (densbits[b * N + j] > bi) {
            const float* p = yb + j;
            float dot = 0.f;
            #pragma unroll 8
            for (int c = 0; c < C; ++c) dot += yi[c] * p[(size_t)c * N];
            float d = ni + ynorm[b * N + j] - 2.f * dot + rel[(size_t)i * N + j];
            mn = fminf(mn, d);
        }
    }
    rv[t] = mn;
    __syncthreads();
    for (int s = 128; s > 0; s >>= 1) {
        if (t < s) rv[t] = fminf(rv[t], rv[t + s]);
        __syncthreads();
    }
    if (t == 0) {
        float dp = fminf(rv[0], dmax[b]);
        double p = (double)dp * (double)__uint_as_float(bi);
        float sf = (float)p;
        uint32_t sb = (sf < 0x1p-126f) ? 0u : __float_as_uint(sf);
        keys[b * N + i] = ((unsigned long long)sb << 32)
                        | (unsigned long long)(0xFFFFFFFFu - (uint32_t)i);
    }
}

// ---------------------------------------------------------------------------
// K4: per-batch bitonic sort of packed keys, descending -> top M indices.
__global__ __launch_bounds__(1024) void k_topm(const unsigned long long* __restrict__ keys,
                                               int* __restrict__ sidx) {
    constexpr int SZ = 4096;
    int b = blockIdx.x, t = threadIdx.x;
    __shared__ unsigned long long ks[SZ];
    for (int i = t; i < SZ; i += 1024) ks[i] = (i < N) ? keys[b * N + i] : 0ull;
    __syncthreads();
    for (int k = 2; k <= SZ; k <<= 1) {
        for (int j = k >> 1; j > 0; j >>= 1) {
            for (int i = t; i < SZ; i += 1024) {
                int ixj = i ^ j;
                if (ixj > i) {
                    bool up = ((i & k) == 0);
                    unsigned long long a = ks[i], c2 = ks[ixj];
                    bool doSwap = up ? (a < c2) : (a > c2);  // descending
                    if (doSwap) { ks[i] = c2; ks[ixj] = a; }
                }
            }
            __syncthreads();
        }
    }
    for (int m = t; m < M; m += 1024)
        sidx[b * M + m] = (int)(0xFFFFFFFFu - (uint32_t)(ks[m] & 0xFFFFFFFFull));
}

// ---------------------------------------------------------------------------
// K5 v2: gather centers TRANSPOSED: cenT[b][c][m] = y[b][c][sidx[m]].
__global__ __launch_bounds__(256) void k_cen(const float* __restrict__ y,
                                             const int* __restrict__ sidx,
                                             const float* __restrict__ ynorm,
                                             float* __restrict__ cenT,
                                             float* __restrict__ cnorm) {
    const int b = blockIdx.y;
    const int m = blockIdx.x * 256 + threadIdx.x;
    if (m >= M) return;
    const int j = sidx[b * M + m];
    cnorm[b * M + m] = ynorm[b * N + j];
    const float* yb = y + (size_t)b * C * N;
    float* ct = cenT + (size_t)b * C * M;
    #pragma unroll 8
    for (int c = 0; c < C; ++c)
        ct[(size_t)c * M + m] = yb[(size_t)c * N + j];
}

// ---------------------------------------------------------------------------
// K6 v3 (xT path, validated round 11)
__global__ __launch_bounds__(256) void k_assign_t(const float* __restrict__ xT,
                                                  const float* __restrict__ cenT,
                                                  const float* __restrict__ xnorm,
                                                  const float* __restrict__ cnorm,
                                                  float* __restrict__ assign,
                                                  int* __restrict__ nnidx) {
    const int b  = blockIdx.y;
    const int i0 = blockIdx.x * 8;
    const int t  = threadIdx.x;

    __shared__ __align__(16) float Ss[8][788];
    __shared__ float xnS[8];

    const float* xTb = xT + (size_t)b * N * C;
    const float* ct  = cenT + (size_t)b * C * M;

    if (t < 8) xnS[t] = xnorm[b * N + i0 + t];
    __syncthreads();

    if (t < 196) {
        const int mt = 4 * t;
        float acc[8][4];
        #pragma unroll
        for (int r = 0; r < 8; ++r)
            #pragma unroll
            for (int q = 0; q < 4; ++q) acc[r][q] = 0.f;

        for (int c0 = 0; c0 < C; c0 += 4) {
            float4 bq0 = *reinterpret_cast<const float4*>(ct + (size_t)(c0 + 0) * M + mt);
            float4 bq1 = *reinterpret_cast<const float4*>(ct + (size_t)(c0 + 1) * M + mt);
            float4 bq2 = *reinterpret_cast<const float4*>(ct + (size_t)(c0 + 2) * M + mt);
            float4 bq3 = *reinterpret_cast<const float4*>(ct + (size_t)(c0 + 3) * M + mt);
            #pragma unroll
            for (int r = 0; r < 8; ++r) {
                float4 a4 = *reinterpret_cast<const float4*>(
                    xTb + (size_t)(i0 + r) * C + c0);   // wave-uniform addr
                acc[r][0] += a4.x * bq0.x; acc[r][1] += a4.x * bq0.y;
                acc[r][2] += a4.x * bq0.z; acc[r][3] += a4.x * bq0.w;
                acc[r][0] += a4.y * bq1.x; acc[r][1] += a4.y * bq1.y;
                acc[r][2] += a4.y * bq1.z; acc[r][3] += a4.y * bq1.w;
                acc[r][0] += a4.z * bq2.x; acc[r][1] += a4.z * bq2.y;
                acc[r][2] += a4.z * bq2.z; acc[r][3] += a4.z * bq2.w;
                acc[r][0] += a4.w * bq3.x; acc[r][1] += a4.w * bq3.y;
                acc[r][2] += a4.w * bq3.z; acc[r][3] += a4.w * bq3.w;
            }
        }

        float4 cn4 = *reinterpret_cast<const float4*>(cnorm + (size_t)b * M + mt);
        float cn[4] = {cn4.x, cn4.y, cn4.z, cn4.w};
        #pragma unroll
        for (int r = 0; r < 8; ++r) {
            float xn = xnS[r];
            float sv[4];
            #pragma unroll
            for (int q = 0; q < 4; ++q)
                sv[q] = -(xn + cn[q] - 2.f * acc[r][q]);
            *reinterpret_cast<float4*>(&Ss[r][mt]) =
                make_float4(sv[0], sv[1], sv[2], sv[3]);
        }
    }
    __syncthreads();

    const int r = t >> 5;
    const int l = t & 31;

    float lm = -FLT_MAX;
    for (int m = l; m < M; m += 32) lm = fmaxf(lm, Ss[r][m]);
    #pragma unroll
    for (int off = 16; off > 0; off >>= 1)
        lm = fmaxf(lm, __shfl_xor(lm, off, 32));
    const float smax = lm;

    float ls = 0.f;
    for (int m = l; m < M; m += 32) ls += expf(Ss[r][m] - smax);
    #pragma unroll
    for (int off = 16; off > 0; off >>= 1)
        ls += __shfl_xor(ls, off, 32);
    const float inv = 1.f / ls;

    float* arow = assign + ((size_t)b * N + i0 + r) * M;
    for (int m = l; m < M; m += 32) arow[m] = expf(Ss[r][m] - smax) * inv;

    for (int round = 0; round < TK; ++round) {
        float lv = -FLT_MAX; int li = M;
        for (int m = l; m < M; m += 32) {
            float v = Ss[r][m];
            if (v > lv) { lv = v; li = m; }
        }
        #pragma unroll
        for (int off = 16; off > 0; off >>= 1) {
            float ov = __shfl_xor(lv, off, 32);
            int   oi = __shfl_xor(li, off, 32);
            if (ov > lv || (ov == lv && oi < li)) { lv = ov; li = oi; }
        }
        if (l == 0) {
            nnidx[((size_t)b * N + i0 + r) * TK + round] = li;
            Ss[r][li] = -FLT_MAX;
        }
        __syncthreads();
    }
}

// ---------------------------------------------------------------------------
// K6 v2 (fallback, validated round 8)
__global__ __launch_bounds__(256) void k_assign(const float* __restrict__ x,
                                                const float* __restrict__ cenT,
                                                const float* __restrict__ xnorm,
                                                const float* __restrict__ cnorm,
                                                float* __restrict__ assign,
                                                int* __restrict__ nnidx) {
    const int b  = blockIdx.y;
    const int i0 = blockIdx.x * 8;
    const int t  = threadIdx.x;

    __shared__ __align__(16) float xiS[8][100];
    __shared__ __align__(16) float Ss[8][788];
    __shared__ float xnS[8];

    const float* xb = x + (size_t)b * C * N;
    const float* ct = cenT + (size_t)b * C * M;

    for (int e = t; e < C * 2; e += 256) {
        int c = e >> 1, n4 = (e & 1) << 2;
        float4 v = *reinterpret_cast<const float4*>(xb + (size_t)c * N + i0 + n4);
        xiS[n4 + 0][c] = v.x;
        xiS[n4 + 1][c] = v.y;
        xiS[n4 + 2][c] = v.z;
        xiS[n4 + 3][c] = v.w;
    }
    if (t < 8) xnS[t] = xnorm[b * N + i0 + t];
    __syncthreads();

    if (t < 196) {
        const int mt = 4 * t;
        float acc[8][4];
        #pragma unroll
        for (int r = 0; r < 8; ++r)
            #pragma unroll
            for (int q = 0; q < 4; ++q) acc[r][q] = 0.f;

        for (int c0 = 0; c0 < C; c0 += 4) {
            float4 bq0 = *reinterpret_cast<const float4*>(ct + (size_t)(c0 + 0) * M + mt);
            float4 bq1 = *reinterpret_cast<const float4*>(ct + (size_t)(c0 + 1) * M + mt);
            float4 bq2 = *reinterpret_cast<const float4*>(ct + (size_t)(c0 + 2) * M + mt);
            float4 bq3 = *reinterpret_cast<const float4*>(ct + (size_t)(c0 + 3) * M + mt);
            #pragma unroll
            for (int r = 0; r < 8; ++r) {
                float4 a4 = *reinterpret_cast<const float4*>(&xiS[r][c0]);
                acc[r][0] += a4.x * bq0.x; acc[r][1] += a4.x * bq0.y;
                acc[r][2] += a4.x * bq0.z; acc[r][3] += a4.x * bq0.w;
                acc[r][0] += a4.y * bq1.x; acc[r][1] += a4.y * bq1.y;
                acc[r][2] += a4.y * bq1.z; acc[r][3] += a4.y * bq1.w;
                acc[r][0] += a4.z * bq2.x; acc[r][1] += a4.z * bq2.y;
                acc[r][2] += a4.z * bq2.z; acc[r][3] += a4.z * bq2.w;
                acc[r][0] += a4.w * bq3.x; acc[r][1] += a4.w * bq3.y;
                acc[r][2] += a4.w * bq3.z; acc[r][3] += a4.w * bq3.w;
            }
        }

        float4 cn4 = *reinterpret_cast<const float4*>(cnorm + (size_t)b * M + mt);
        float cn[4] = {cn4.x, cn4.y, cn4.z, cn4.w};
        #pragma unroll
        for (int r = 0; r < 8; ++r) {
            float xn = xnS[r];
            float sv[4];
            #pragma unroll
            for (int q = 0; q < 4; ++q)
                sv[q] = -(xn + cn[q] - 2.f * acc[r][q]);
            *reinterpret_cast<float4*>(&Ss[r][mt]) =
                make_float4(sv[0], sv[1], sv[2], sv[3]);
        }
    }
    __syncthreads();

    const int r = t >> 5;
    const int l = t & 31;

    float lm = -FLT_MAX;
    for (int m = l; m < M; m += 32) lm = fmaxf(lm, Ss[r][m]);
    #pragma unroll
    for (int off = 16; off > 0; off >>= 1)
        lm = fmaxf(lm, __shfl_xor(lm, off, 32));
    const float smax = lm;

    float ls = 0.f;
    for (int m = l; m < M; m += 32) ls += expf(Ss[r][m] - smax);
    #pragma unroll
    for (int off = 16; off > 0; off >>= 1)
        ls += __shfl_xor(ls, off, 32);
    const float inv = 1.f / ls;

    float* arow = assign + ((size_t)b * N + i0 + r) * M;
    for (int m = l; m < M; m += 32) arow[m] = expf(Ss[r][m] - smax) * inv;

    for (int round = 0; round < TK; ++round) {
        float lv = -FLT_MAX; int li = M;
        for (int m = l; m < M; m += 32) {
            float v = Ss[r][m];
            if (v > lv) { lv = v; li = m; }
        }
        #pragma unroll
        for (int off = 16; off > 0; off >>= 1) {
            float ov = __shfl_xor(lv, off, 32);
            int   oi = __shfl_xor(li, off, 32);
            if (ov > lv || (ov == lv && oi < li)) { lv = ov; li = oi; }
        }
        if (l == 0) {
            nnidx[((size_t)b * N + i0 + r) * TK + round] = li;
            Ss[r][li] = -FLT_MAX;
        }
        __syncthreads();
    }
}

// ---------------------------------------------------------------------------
// K7a v2: partial agg over an n-slice with 4m x 3c register tiling.
__global__ __launch_bounds__(128) void k_agg_part(const float* __restrict__ assign,
                                                  const float* __restrict__ x,
                                                  float* __restrict__ aggpart,
                                                  float* __restrict__ masspart) {
    const int b = blockIdx.z;
    const int s = blockIdx.y;
    const int m0 = blockIdx.x * 16;
    const int t = threadIdx.x;
    __shared__ __align__(16) float As[64][16];
    __shared__ __align__(16) float Xs[96][68];   // 68-pad: rows 16B-aligned

    const int mm = 4 * (t & 3);        // 0,4,8,12
    const int cc = 3 * (t >> 2);       // 0..93 step 3

    float acc[4][3];
    #pragma unroll
    for (int i = 0; i < 4; ++i)
        #pragma unroll
        for (int j = 0; j < 3; ++j) acc[i][j] = 0.f;
    float massacc = 0.f;

    const int nbeg = s * (N / NSPLIT);
    const int nend = nbeg + (N / NSPLIT);

    for (int n0 = nbeg; n0 < nend; n0 += 64) {
        #pragma unroll
        for (int k = 0; k < 2; ++k) {
            int idx = t + k * 128;
            int nn = idx >> 2, mq = idx & 3;
            *reinterpret_cast<float4*>(&As[nn][4 * mq]) =
                *reinterpret_cast<const float4*>(
                    assign + ((size_t)b * N + n0 + nn) * M + m0 + 4 * mq);
        }
        #pragma unroll
        for (int k = 0; k < 12; ++k) {
            int idx = t + k * 128;
            int c = idx >> 4, nq = idx & 15;
            *reinterpret_cast<float4*>(&Xs[c][4 * nq]) =
                *reinterpret_cast<const float4*>(
                    x + ((size_t)b * C + c) * N + n0 + 4 * nq);
        }
        __syncthreads();

        if (t < 16) {
            #pragma unroll
            for (int nn = 0; nn < 64; ++nn) massacc += As[nn][t];
        }

        #pragma unroll 4
        for (int nn = 0; nn < 64; ++nn) {
            float4 a4 = *reinterpret_cast<const float4*>(&As[nn][mm]);
            float x0 = Xs[cc + 0][nn];
            float x1 = Xs[cc + 1][nn];
            float x2 = Xs[cc + 2][nn];
            acc[0][0] += a4.x * x0; acc[0][1] += a4.x * x1; acc[0][2] += a4.x * x2;
            acc[1][0] += a4.y * x0; acc[1][1] += a4.y * x1; acc[1][2] += a4.y * x2;
            acc[2][0] += a4.z * x0; acc[2][1] += a4.z * x1; acc[2][2] += a4.z * x2;
            acc[3][0] += a4.w * x0; acc[3][1] += a4.w * x1; acc[3][2] += a4.w * x2;
        }
        __syncthreads();
    }
    if (t < 16) masspart[((size_t)b * NSPLIT + s) * M + m0 + t] = massacc;
    float* ap = aggpart + (((size_t)b * NSPLIT + s) * M) * C;
    #pragma unroll
    for (int i = 0; i < 4; ++i)
        #pragma unroll
        for (int j = 0; j < 3; ++j)
            ap[(size_t)(m0 + mm + i) * C + cc + j] = acc[i][j];
}

// ---------------------------------------------------------------------------
// K7b: reduce the NSPLIT partials (fixed s order), divide by mass+1e-6.
__global__ __launch_bounds__(256) void k_aggred(const float* __restrict__ aggpart,
                                                const float* __restrict__ masspart,
                                                float* __restrict__ aggws) {
    const int b = blockIdx.y;
    const int e = blockIdx.x * 256 + threadIdx.x;   // e = m*C + c
    if (e >= M * C) return;
    const int m = e / C;
    float a = 0.f, ms = 0.f;
    #pragma unroll
    for (int s = 0; s < NSPLIT; ++s) {
        a  += aggpart[(((size_t)b * NSPLIT + s) * M) * C + e];
        ms += masspart[((size_t)b * NSPLIT + s) * M + m];
    }
    aggws[(size_t)b * M * C + e] = a / (ms + 1e-6f);
}

// ---------------------------------------------------------------------------
// K8 v2: batched-GEMM FFN. 8 centers/block, 256 threads, register tiling.
__global__ __launch_bounds__(256) void k_ffn(const float* __restrict__ w1,
                                             const float* __restrict__ b1,
                                             const float* __restrict__ g1,
                                             const float* __restrict__ bt1,
                                             const float* __restrict__ w2,
                                             const float* __restrict__ b2,
                                             const float* __restrict__ g2,
                                             const float* __restrict__ bt2,
                                             float* __restrict__ aggws,
                                             float* __restrict__ refined) {
    const int m0 = blockIdx.x * 8;
    const int b  = blockIdx.y;
    const int t  = threadIdx.x;

    __shared__ __align__(16) float arS[8][100];
    __shared__ __align__(16) float hdS[8][388];

    const float* abase = aggws + ((size_t)b * M + m0) * C;
    if (t < 192) {
        float4 v = *reinterpret_cast<const float4*>(abase + 4 * t);
        int e = 4 * t;
        int m = e / C, c = e % C;
        *reinterpret_cast<float4*>(&arS[m][c]) = v;
    }
    __syncthreads();

    {
        const int og = t >> 1;            // 0..127
        const int mg = (t & 1) * 4;       // 0 or 4
        float acc[3][4];
        #pragma unroll
        for (int j = 0; j < 3; ++j)
            #pragma unroll
            for (int i = 0; i < 4; ++i) acc[j][i] = 0.f;

        for (int c0 = 0; c0 < C; c0 += 4) {
            float4 a0 = *reinterpret_cast<const float4*>(&arS[mg + 0][c0]);
            float4 a1 = *reinterpret_cast<const float4*>(&arS[mg + 1][c0]);
            float4 a2 = *reinterpret_cast<const float4*>(&arS[mg + 2][c0]);
            float4 a3 = *reinterpret_cast<const float4*>(&arS[mg + 3][c0]);
            #pragma unroll
            for (int j = 0; j < 3; ++j) {
                float4 w4 = *reinterpret_cast<const float4*>(
                    w1 + (size_t)(og + 128 * j) * C + c0);
                acc[j][0] += w4.x * a0.x; acc[j][0] += w4.y * a0.y;
                acc[j][0] += w4.z * a0.z; acc[j][0] += w4.w * a0.w;
                acc[j][1] += w4.x * a1.x; acc[j][1] += w4.y * a1.y;
                acc[j][1] += w4.z * a1.z; acc[j][1] += w4.w * a1.w;
                acc[j][2] += w4.x * a2.x; acc[j][2] += w4.y * a2.y;
                acc[j][2] += w4.z * a2.z; acc[j][2] += w4.w * a2.w;
                acc[j][3] += w4.x * a3.x; acc[j][3] += w4.y * a3.y;
                acc[j][3] += w4.z * a3.z; acc[j][3] += w4.w * a3.w;
            }
        }
        #pragma unroll
        for (int j = 0; j < 3; ++j) {
            const int o = og + 128 * j;
            const float bb = b1[o], gg = g1[o], bt = bt1[o];
            #pragma unroll
            for (int i = 0; i < 4; ++i) {
                float h = (acc[j][i] + bb) * gg + bt;
                hdS[mg + i][o] = fmaxf(h, 0.f);
            }
        }
    }
    __syncthreads();

    {
        const int m = t >> 5;             // 0..7
        const int l = t & 31;             // c base
        float acc2[3] = {0.f, 0.f, 0.f};

        for (int o0 = 0; o0 < C4; o0 += 4) {
            float4 h4 = *reinterpret_cast<const float4*>(&hdS[m][o0]);
            #pragma unroll
            for (int j = 0; j < 3; ++j) {
                float4 w4 = *reinterpret_cast<const float4*>(
                    w2 + (size_t)(l + 32 * j) * C4 + o0);
                acc2[j] += w4.x * h4.x; acc2[j] += w4.y * h4.y;
                acc2[j] += w4.z * h4.z; acc2[j] += w4.w * h4.w;
            }
        }
        #pragma unroll
        for (int j = 0; j < 3; ++j) {
            const int c = l + 32 * j;
            float f = acc2[j] + b2[c];
            float v = arS[m][c] + (f * g2[c] + bt2[c]);
            aggws[((size_t)b * M + m0 + m) * C + c] = v;
            refined[((size_t)b * C + c) * M + m0 + m] = v;
        }
    }
}

// ---------------------------------------------------------------------------
// K9: rel = max over top-5 agg rows - xf; interleaved xcat;
// out = relu((nn_w @ xcat + nn_b) * g + bt), stored (B, OUT, N)
__global__ __launch_bounds__(256) void k_final(const float* __restrict__ x,
                                               const float* __restrict__ aggws,
                                               const int* __restrict__ nnidx,
                                               const float* __restrict__ nnw,
                                               const float* __restrict__ nnb,
                                               const float* __restrict__ nng,
                                               const float* __restrict__ nnbt,
                                               float* __restrict__ out) {
    const int b = blockIdx.y;
    const int n0 = blockIdx.x * 16;
    const int t = threadIdx.x;
    __shared__ float xc[16][193];
    __shared__ int nid[16 * TK];

    if (t < 16 * TK) nid[t] = nnidx[((size_t)b * N + n0) * TK + t];
    __syncthreads();

    for (int e = t; e < C * 16; e += 256) {
        int c = e >> 4, r = e & 15;
        float xv = x[((size_t)b * C + c) * N + n0 + r];
        float mx = -FLT_MAX;
        #pragma unroll
        for (int k = 0; k < TK; ++k) {
            int j = nid[r * TK + k];
            mx = fmaxf(mx, aggws[((size_t)b * M + j) * C + c]);
        }
        xc[r][2 * c]     = xv;
        xc[r][2 * c + 1] = mx - xv;
    }
    __syncthreads();

    const int r = t & 15;
    const int og = t >> 4;
    #pragma unroll
    for (int oo = 0; oo < 12; ++oo) {
        int o = og + (oo << 4);
        const float* w = nnw + (size_t)o * (2 * C);
        float a = nnb[o];
        #pragma unroll 8
        for (int cc = 0; cc < 2 * C; ++cc) a += w[cc] * xc[r][cc];
        a = a * nng[o] + nnbt[o];
        out[((size_t)b * OUT + o) * N + n0 + r] = fmaxf(a, 0.f);
    }
}

// ---------------------------------------------------------------------------
extern "C" void kernel_launch(void* const* d_in, const int* in_sizes, int n_in,
                              void* d_out, int out_size, void* d_ws, size_t ws_size,
                              hipStream_t stream) {
    const float* x    = (const float*)d_in[0];
    const float* rel  = (const float*)d_in[1];
    const float* y    = (const float*)d_in[2];
    const float* w1   = (const float*)d_in[3];
    const float* b1   = (const float*)d_in[4];
    const float* g1   = (const float*)d_in[5];
    const float* bt1  = (const float*)d_in[6];
    const float* w2   = (const float*)d_in[7];
    const float* b2   = (const float*)d_in[8];
    const float* g2   = (const float*)d_in[9];
    const float* bt2  = (const float*)d_in[10];
    const float* nnw  = (const float*)d_in[11];
    const float* nnb  = (const float*)d_in[12];
    const float* nng  = (const float*)d_in[13];
    const float* nnbt = (const float*)d_in[14];

    float* out     = (float*)d_out;
    float* refined = out + (size_t)B * OUT * N;

    char* w = (char*)d_ws;
    auto alloc = [&](size_t nbytes) -> void* {
        void* p = (void*)w;
        w += (nbytes + 255) & ~(size_t)255;
        return p;
    };
    float*    ynorm    = (float*)   alloc((size_t)B * N * 4);
    float*    xnorm    = (float*)   alloc((size_t)B * N * 4);
    uint32_t* densbits = (uint32_t*)alloc((size_t)B * N * 4);
    float*    rowmax   = (float*)   alloc((size_t)B * N * 4);
    float*    dmaxv    = (float*)   alloc((size_t)B * 4);
    unsigned long long* keys = (unsigned long long*)alloc((size_t)B * N * 8);
    int*      sidx     = (int*)     alloc((size_t)B * M * 4);
    float*    cnorm    = (float*)   alloc((size_t)B * M * 4);
    float*    cenT     = (float*)   alloc((size_t)B * C * M * 4);
    float*    aggws    = (float*)   alloc((size_t)B * M * C * 4);
    int*      nnidx    = (int*)     alloc((size_t)B * N * TK * 4);
    float*    assign   = (float*)   alloc((size_t)B * N * M * 4);
    float*    aggpart  = (float*)   alloc((size_t)B * NSPLIT * M * C * 4);
    float*    masspart = (float*)   alloc((size_t)B * NSPLIT * M * 4);

    // optional transposed + bf16-fragment copies (gated on workspace size)
    size_t used = (size_t)(w - (char*)d_ws);
    size_t tbytes = (size_t)B * N * C * 4;
    size_t fragbytes = (size_t)B * NT16 * 3 * 64 * 8 * sizeof(ushort);
    float* yT = nullptr;
    float* xT = nullptr;
    ushort* yfrag = nullptr;
    if (ws_size >= used + 2 * (tbytes + 256) + (fragbytes + 256)) {
        yT = (float*)alloc(tbytes);
        xT = (float*)alloc(tbytes);
        yfrag = (ushort*)alloc(fragbytes);
    } else if (ws_size >= used + 2 * (tbytes + 256)) {
        yT = (float*)alloc(tbytes);
        xT = (float*)alloc(tbytes);
    }

    if (yT) k_tr<<<dim3(N / 32, C / 32, B), dim3(256), 0, stream>>>(y, x, yT, xT);
    if (yfrag) k_yfrag<<<dim3(NT16, B), dim3(192), 0, stream>>>(y, yfrag);

    k_norms<<<dim3((B * N + 255) / 256), dim3(256), 0, stream>>>(y, x, ynorm, xnorm);

    if (yT && yfrag)
        k_density_mfma<<<dim3(N / 16, B), dim3(256), 0, stream>>>(yT, yfrag, rel, ynorm, densbits, rowmax);
    else
        k_density<<<dim3(N / DR, B), dim3(256), 0, stream>>>(y, rel, ynorm, densbits, rowmax);

    k_dmax<<<dim3(B), dim3(256), 0, stream>>>(rowmax, dmaxv);
    k_score<<<dim3(N, B), dim3(256), 0, stream>>>(y, rel, ynorm, densbits, dmaxv, keys);
    k_topm<<<dim3(B), dim3(1024), 0, stream>>>(keys, sidx);
    k_cen<<<dim3((M + 255) / 256, B), dim3(256), 0, stream>>>(y, sidx, ynorm, cenT, cnorm);

    if (xT)
        k_assign_t<<<dim3(N / 8, B), dim3(256), 0, stream>>>(xT, cenT, xnorm, cnorm, assign, nnidx);
    else
        k_assign<<<dim3(N / 8, B), dim3(256), 0, stream>>>(x, cenT, xnorm, cnorm, assign, nnidx);

    k_agg_part<<<dim3(M / 16, NSPLIT, B), dim3(128), 0, stream>>>(assign, x, aggpart, masspart);
    k_aggred<<<dim3((M * C + 255) / 256, B), dim3(256), 0, stream>>>(aggpart, masspart, aggws);
    k_ffn<<<dim3(M / 8, B), dim3(256), 0, stream>>>(w1, b1, g1, bt1, w2, b2, g2, bt2, aggws, refined);
    k_final<<<dim3(N / 16, B), dim3(256), 0, stream>>>(x, aggws, nnidx, nnw, nnb, nng, nnbt, out);
}